// Round 8
// baseline (396.938 us; speedup 1.0000x reference)
//
#include <hip/hip_runtime.h>

// Problem constants (from reference)
#define N_NODES 100000
#define F_IN    128
#define H_DIM   128
#define Z_DIM   64
#define E_EDGES 1600000
#define EP_EDGES 200000

// bucket sort params: bucket = dst >> 7  (128 nodes/bucket)
#define BSHIFT 7
#define NBUCK  ((N_NODES + 127) >> 7)          // 782
#define CHUNK  4096
#define NCHUNK ((E_EDGES + CHUNK - 1) / CHUNK) // 391

typedef __attribute__((ext_vector_type(8))) short short8;   // 8 bf16 = 4 VGPRs
typedef __attribute__((ext_vector_type(4))) float f32x4;    // MFMA C/D frag
typedef unsigned int uint;
typedef unsigned short ushort;

// bf16 helpers (round-to-nearest-even)
__device__ __forceinline__ ushort f2bf(float f) {
    uint u = __float_as_uint(f);
    u += 0x7fffu + ((u >> 16) & 1u);
    return (ushort)(u >> 16);
}
__device__ __forceinline__ float bflo(uint u) { return __uint_as_float(u << 16); }
__device__ __forceinline__ float bfhi(uint u) { return __uint_as_float(u & 0xffff0000u); }

// ---------------- weight prep (+ gcur zeroing folded in) ----------------

__global__ __launch_bounds__(256) void wprep_kernel(const float* __restrict__ W1,
                                                    const float* __restrict__ W2,
                                                    ushort* __restrict__ W1T,
                                                    ushort* __restrict__ W2T,
                                                    int* __restrict__ gcur) {
    int i = blockIdx.x * 256 + threadIdx.x;
    if (i < 1024) gcur[i] = 0;               // zero bucket totals
    if (i < 128 * 128) {
        int n = i >> 7, k = i & 127;
        W1T[i] = f2bf(W1[k * 128 + n]);
    }
    int j = i - 128 * 128;
    if (j >= 0 && j < 64 * 128) {
        int n = j >> 7, k = j & 127;
        W2T[j] = f2bf(W2[k * 64 + n]);
    }
}

// ---------------- bucket histogram: per-chunk LDS hist -> tbl + totals -----

__global__ __launch_bounds__(256) void bhist_kernel(const int* __restrict__ dst,
                                                    int* __restrict__ gcur,
                                                    int* __restrict__ tbl) {
    __shared__ int lh[NBUCK];
    for (int i = threadIdx.x; i < NBUCK; i += 256) lh[i] = 0;
    __syncthreads();
    int base = blockIdx.x * CHUNK;
    int end = min(base + CHUNK, E_EDGES);
    for (int e = base + threadIdx.x; e < end; e += 256)
        atomicAdd(&lh[dst[e] >> BSHIFT], 1);
    __syncthreads();
    int* trow = tbl + (size_t)blockIdx.x * NBUCK;
    for (int i = threadIdx.x; i < NBUCK; i += 256) {
        int c = lh[i];
        trow[i] = c;                         // per-chunk count (coalesced)
        if (c) atomicAdd(&gcur[i], c);       // bucket total
    }
}

// ---------------- exclusive scan over 782 bucket totals (single block) -----

__global__ __launch_bounds__(1024) void bscan_kernel(int* __restrict__ gc) {
    __shared__ int s[1024];
    int t = threadIdx.x;
    int v = (t < NBUCK) ? gc[t] : 0;
    s[t] = v;
    __syncthreads();
    #pragma unroll
    for (int off = 1; off < 1024; off <<= 1) {
        int x = (t >= off) ? s[t - off] : 0;
        __syncthreads();
        s[t] += x;
        __syncthreads();
    }
    if (t < NBUCK) gc[t] = s[t] - v;   // exclusive prefix = bucket starts
}

// ---------------- per-bucket scan over chunk counts ----------------

__global__ __launch_bounds__(512) void chunk_scan_kernel(int* __restrict__ tbl,
                                                         const int* __restrict__ gcur) {
    __shared__ int s[512];
    int b = blockIdx.x, t = threadIdx.x;
    int v = (t < NCHUNK) ? tbl[(size_t)t * NBUCK + b] : 0;
    s[t] = v;
    __syncthreads();
    #pragma unroll
    for (int off = 1; off < 512; off <<= 1) {
        int x = (t >= off) ? s[t - off] : 0;
        __syncthreads();
        s[t] += x;
        __syncthreads();
    }
    if (t < NCHUNK)
        tbl[(size_t)t * NBUCK + b] = gcur[b] + (s[t] - v);  // absolute base
}

// ---------------- bucket scatter: single pass, no global atomics -----------
// packed = (src << 7) | (dst & 127): src < 2^17, local dst 7 bits.

__global__ __launch_bounds__(256) void bscatter_kernel(const int* __restrict__ src,
                                                       const int* __restrict__ dst,
                                                       const int* __restrict__ tbl,
                                                       int* __restrict__ sorted) {
    __shared__ int lbase[NBUCK];
    int c = blockIdx.x;
    const int* trow = tbl + (size_t)c * NBUCK;
    for (int i = threadIdx.x; i < NBUCK; i += 256) lbase[i] = trow[i];  // coalesced
    __syncthreads();
    int base = c * CHUNK;
    int end = min(base + CHUNK, E_EDGES);
    for (int e = base + threadIdx.x; e < end; e += 256) {
        int d = dst[e];
        int p = atomicAdd(&lbase[d >> BSHIFT], 1);
        sorted[p] = (src[e] << 7) | (d & 127);
    }
}

// ---------------- fused per-bucket CSR build (per-wave hist/cursors) -------

__global__ __launch_bounds__(256) void bucket_csr_kernel(const int* __restrict__ sorted,
                                                         const int* __restrict__ gcur,
                                                         int* __restrict__ csr,
                                                         int* __restrict__ ends,
                                                         float* __restrict__ dinv) {
    __shared__ int lcnt[4][128], lcur[4][128];
    int b = blockIdx.x, t = threadIdx.x;
    int wave = t >> 6;
    int bstart = gcur[b];
    int bend = (b + 1 < NBUCK) ? gcur[b + 1] : E_EDGES;
    if (t < 128) { lcnt[0][t] = 0; lcnt[1][t] = 0; }
    else { int u = t - 128; lcnt[2][u] = 0; lcnt[3][u] = 0; }
    __syncthreads();
    for (int i = bstart + t; i < bend; i += 256)
        atomicAdd(&lcnt[wave][sorted[i] & 127], 1);
    __syncthreads();
    if (t < 64) {                         // wave 0: scan 128 node totals
        int w0a = lcnt[0][t], w1a = lcnt[1][t], w2a = lcnt[2][t], w3a = lcnt[3][t];
        int w0b = lcnt[0][t + 64], w1b = lcnt[1][t + 64], w2b = lcnt[2][t + 64], w3b = lcnt[3][t + 64];
        int c0 = w0a + w1a + w2a + w3a;
        int c1 = w0b + w1b + w2b + w3b;
        int s0 = c0;
        #pragma unroll
        for (int d = 1; d < 64; d <<= 1) {
            int x = __shfl_up(s0, d, 64);
            if (t >= d) s0 += x;
        }
        int tot0 = __shfl(s0, 63, 64);
        int s1 = c1;
        #pragma unroll
        for (int d = 1; d < 64; d <<= 1) {
            int x = __shfl_up(s1, d, 64);
            if (t >= d) s1 += x;
        }
        s1 += tot0;
        int basea = bstart + s0 - c0;     // start of node t
        int baseb = bstart + s1 - c1;     // start of node t+64
        lcur[0][t] = basea;
        lcur[1][t] = basea + w0a;
        lcur[2][t] = basea + w0a + w1a;
        lcur[3][t] = basea + w0a + w1a + w2a;
        lcur[0][t + 64] = baseb;
        lcur[1][t + 64] = baseb + w0b;
        lcur[2][t + 64] = baseb + w0b + w1b;
        lcur[3][t + 64] = baseb + w0b + w1b + w2b;
        int n0 = b * 128 + t, n1 = n0 + 64;
        if (n0 < N_NODES) { ends[n0] = bstart + s0; dinv[n0] = rsqrtf(1.0f + (float)c0); }
        if (n1 < N_NODES) { ends[n1] = bstart + s1; dinv[n1] = rsqrtf(1.0f + (float)c1); }
    }
    __syncthreads();
    for (int i = bstart + t; i < bend; i += 256) {
        int v = sorted[i];
        int p = atomicAdd(&lcur[wave][v & 127], 1);
        csr[p] = v >> 7;
    }
}

// ---------------- MFMA bf16 GEMM with dinv-prescaled bf16 output ----------

template<int NC, bool A_F32>
__global__ __launch_bounds__(256) void gemm_mfma_kernel(const void* __restrict__ Ap,
                                                        const ushort* __restrict__ BT,
                                                        const float* __restrict__ dinv,
                                                        ushort* __restrict__ C, int M) {
    constexpr int NT = NC / 16;
    __shared__ ushort Bs[4 * NT * 64 * 8];   // 32KB (NC=128) / 16KB (NC=64)

    for (int idx = threadIdx.x; idx < 4 * NT * 64; idx += 256) {
        int l   = idx & 63;
        int nt  = (idx >> 6) % NT;
        int kc  = idx / (64 * NT);
        int m16 = l & 15, quad = l >> 4;
        ((short8*)Bs)[idx] =
            *(const short8*)(BT + ((nt * 16 + m16) * 128 + kc * 32 + quad * 8));
    }
    __syncthreads();

    int wave = threadIdx.x >> 6, lane = threadIdx.x & 63;
    int m16 = lane & 15, quad = lane >> 4;
    int row0 = (blockIdx.x * 4 + wave) * 16;
    if (row0 >= M) return;
    int arow = row0 + m16;
    if (arow >= M) arow = M - 1;           // clamp loads; stores guarded

    f32x4 acc[NT];
    #pragma unroll
    for (int t = 0; t < NT; ++t) acc[t] = (f32x4){0.f, 0.f, 0.f, 0.f};

    #pragma unroll
    for (int kc = 0; kc < 4; ++kc) {
        short8 a;
        if (A_F32) {
            const float* A = (const float*)Ap;
            const float4* p = (const float4*)(A + (size_t)arow * 128 + kc * 32 + quad * 8);
            float4 x0 = p[0], x1 = p[1];
            a[0] = (short)f2bf(x0.x); a[1] = (short)f2bf(x0.y);
            a[2] = (short)f2bf(x0.z); a[3] = (short)f2bf(x0.w);
            a[4] = (short)f2bf(x1.x); a[5] = (short)f2bf(x1.y);
            a[6] = (short)f2bf(x1.z); a[7] = (short)f2bf(x1.w);
        } else {
            a = *(const short8*)((const ushort*)Ap + (size_t)arow * 128 + kc * 32 + quad * 8);
        }
        #pragma unroll
        for (int nt = 0; nt < NT; ++nt) {
            short8 b = ((const short8*)Bs)[(kc * NT + nt) * 64 + lane];
            acc[nt] = __builtin_amdgcn_mfma_f32_16x16x32_bf16(a, b, acc[nt], 0, 0, 0);
        }
    }

    #pragma unroll
    for (int r = 0; r < 4; ++r) {
        int row = row0 + quad * 4 + r;
        if (row < M) {
            float dr = dinv[row];
            #pragma unroll
            for (int nt = 0; nt < NT; ++nt)
                C[(size_t)row * NC + nt * 16 + m16] = f2bf(acc[nt][r] * dr);
        }
    }
}

// ---------------- gather FD=128, FEATURE-HALF split ------------------------
// Working-set experiment: FETCH(190MB) is L2 capacity-miss traffic against
// the 25.6MB table (4MB/XCD L2, measured 54% hit). Split the gather over
// feature halves: blocks 0..24999 process channels 0-63 (working set
// 12.8MB), blocks 25000..49999 channels 64-127 — block dispatch order
// gives temporal separation, so steady-state L2 hit rate rises. Costs:
// csr read twice (+6.4MB), ~1.5x per-edge VALU (35% busy -> headroom).
// Per half: half-wave edge pairing (g=lane>>5 picks edge parity, c=lane&31
// is the uint column of the 128B half-row), indices wave-uniform via
// readlane; one shfl_xor(32) merges parities. 4 loads (8 edges) in flight.

__global__ __launch_bounds__(256, 8) void gather128h_kernel(const ushort* __restrict__ feat,
                                                            const float* __restrict__ bias,
                                                            const float* __restrict__ dinv,
                                                            const int* __restrict__ ends,
                                                            const int* __restrict__ csr,
                                                            ushort* __restrict__ out) {
    int wave = threadIdx.x >> 6, lane = threadIdx.x & 63;
    int g = lane >> 5, c = lane & 31;               // edge parity, uint column
    int half = blockIdx.x / (N_NODES / 4);          // 0 or 1 (temporal split)
    int n = (blockIdx.x % (N_NODES / 4)) * 4 + wave;
    const uint* F = (const uint*)feat + half * 32;  // column offset; row stride 64 uints

    float a0 = 0.f, a1 = 0.f;
    uint su = F[(uint)n * 64u + (uint)c];           // self (same addr both parities)
    if (g == 0) { a0 = bflo(su); a1 = bfhi(su); }

    int j0 = n ? ends[n - 1] : 0, j1 = ends[n];
    j0 = __builtin_amdgcn_readfirstlane(j0);
    j1 = __builtin_amdgcn_readfirstlane(j1);

    for (int base = j0; base < j1; base += 64) {
        int m = min(64, j1 - base);
        int idxv = __builtin_nontemporal_load(csr + base + min(lane, m - 1));
        int e = 0;
        for (; e + 8 <= m; e += 8) {                // 4 pair-loads = 8 edges
            int sa0 = __builtin_amdgcn_readlane(idxv, e + 0);
            int sb0 = __builtin_amdgcn_readlane(idxv, e + 1);
            int sa1 = __builtin_amdgcn_readlane(idxv, e + 2);
            int sb1 = __builtin_amdgcn_readlane(idxv, e + 3);
            int sa2 = __builtin_amdgcn_readlane(idxv, e + 4);
            int sb2 = __builtin_amdgcn_readlane(idxv, e + 5);
            int sa3 = __builtin_amdgcn_readlane(idxv, e + 6);
            int sb3 = __builtin_amdgcn_readlane(idxv, e + 7);
            uint p0 = (uint)(g ? sb0 : sa0);
            uint p1 = (uint)(g ? sb1 : sa1);
            uint p2 = (uint)(g ? sb2 : sa2);
            uint p3 = (uint)(g ? sb3 : sa3);
            uint r0 = F[p0 * 64u + (uint)c];
            uint r1 = F[p1 * 64u + (uint)c];
            uint r2 = F[p2 * 64u + (uint)c];
            uint r3 = F[p3 * 64u + (uint)c];
            a0 += bflo(r0) + bflo(r1);
            a1 += bfhi(r0) + bfhi(r1);
            a0 += bflo(r2) + bflo(r3);
            a1 += bfhi(r2) + bfhi(r3);
        }
        for (; e + 2 <= m; e += 2) {                // pair tail
            int sa = __builtin_amdgcn_readlane(idxv, e);
            int sb = __builtin_amdgcn_readlane(idxv, e + 1);
            uint p = (uint)(g ? sb : sa);
            uint r = F[p * 64u + (uint)c];
            a0 += bflo(r); a1 += bfhi(r);
        }
        if (e < m) {                                // single leftover edge
            int s = __builtin_amdgcn_readlane(idxv, e);
            uint r = F[(uint)s * 64u + (uint)c];
            if (g == 0) { a0 += bflo(r); a1 += bfhi(r); }
        }
    }
    a0 += __shfl_xor(a0, 32, 64);
    a1 += __shfl_xor(a1, 32, 64);
    if (g == 0) {
        float dn = dinv[n];
        float2 bv = ((const float2*)bias)[half * 32 + c];
        float o0 = fmaxf(bv.x + dn * a0, 0.f);
        float o1 = fmaxf(bv.y + dn * a1, 0.f);
        ((uint*)out)[(uint)n * 64u + (uint)(half * 32 + c)] =
            (uint)f2bf(o0) | ((uint)f2bf(o1) << 16);
    }
}

// ---------------- gather FD=64, FEATURE-HALF split -------------------------
// Same working-set trick: table 12.8MB -> 6.4MB halves. Quarter-wave rows:
// q=lane>>4 picks one of 4 edges, c=lane&15 is the uint column of the 64B
// half-row. Indices via readlane + 3 cndmask; reduce = shfl_xor 16 + 32.

__global__ __launch_bounds__(256, 8) void gather64h_kernel(const ushort* __restrict__ feat,
                                                           const float* __restrict__ bias,
                                                           const float* __restrict__ dinv,
                                                           const int* __restrict__ ends,
                                                           const int* __restrict__ csr,
                                                           ushort* __restrict__ outB) {
    int wave = threadIdx.x >> 6, lane = threadIdx.x & 63;
    int q = lane >> 4, c = lane & 15;               // edge slot, uint column
    int half = blockIdx.x / (N_NODES / 4);
    int n = (blockIdx.x % (N_NODES / 4)) * 4 + wave;
    const uint* F = (const uint*)feat + half * 16;  // column offset; row stride 32 uints

    float a0 = 0.f, a1 = 0.f;
    uint su = F[(uint)n * 32u + (uint)c];
    if (q == 0) { a0 = bflo(su); a1 = bfhi(su); }

    int j0 = n ? ends[n - 1] : 0, j1 = ends[n];
    j0 = __builtin_amdgcn_readfirstlane(j0);
    j1 = __builtin_amdgcn_readfirstlane(j1);

    for (int base = j0; base < j1; base += 64) {
        int m = min(64, j1 - base);
        int idxv = __builtin_nontemporal_load(csr + base + min(lane, m - 1));
        int e = 0;
        for (; e + 16 <= m; e += 16) {              // 16 edges, 4 loads in flight
            #pragma unroll
            for (int gk = 0; gk < 4; ++gk) {
                int eb = e + gk * 4;
                int s0 = __builtin_amdgcn_readlane(idxv, eb + 0);
                int s1 = __builtin_amdgcn_readlane(idxv, eb + 1);
                int s2 = __builtin_amdgcn_readlane(idxv, eb + 2);
                int s3 = __builtin_amdgcn_readlane(idxv, eb + 3);
                int s = (q < 2) ? (q == 0 ? s0 : s1) : (q == 2 ? s2 : s3);
                uint r = F[(uint)s * 32u + (uint)c];
                a0 += bflo(r); a1 += bfhi(r);
            }
        }
        for (; e < m; e += 4) {                     // tail: clamped readlanes,
            int mc = m - 1;                         // predicated adds
            int s0 = __builtin_amdgcn_readlane(idxv, min(e + 0, mc));
            int s1 = __builtin_amdgcn_readlane(idxv, min(e + 1, mc));
            int s2 = __builtin_amdgcn_readlane(idxv, min(e + 2, mc));
            int s3 = __builtin_amdgcn_readlane(idxv, min(e + 3, mc));
            int s = (q < 2) ? (q == 0 ? s0 : s1) : (q == 2 ? s2 : s3);
            uint r = F[(uint)s * 32u + (uint)c];
            if (e + q < m) { a0 += bflo(r); a1 += bfhi(r); }
        }
    }
    a0 += __shfl_xor(a0, 16, 64); a0 += __shfl_xor(a0, 32, 64);
    a1 += __shfl_xor(a1, 16, 64); a1 += __shfl_xor(a1, 32, 64);
    if (q == 0) {
        float dn = dinv[n];
        float2 bv = ((const float2*)bias)[half * 16 + c];
        float o0 = bv.x + dn * a0;
        float o1 = bv.y + dn * a1;
        ((uint*)outB)[(uint)n * 32u + (uint)(half * 16 + c)] =
            (uint)f2bf(o0) | ((uint)f2bf(o1) << 16);
    }
}

// ---------------- decoder: bf16 latent, half-wave per edge, 8 edges/wave ---

__global__ __launch_bounds__(256) void decode_kernel(const ushort* __restrict__ latentB,
                                                     const int* __restrict__ pos,
                                                     const int* __restrict__ neg,
                                                     float* __restrict__ out) {
    int gwave = (blockIdx.x * 256 + threadIdx.x) >> 6;
    int lane = threadIdx.x & 63;
    int half = lane >> 5, sl = lane & 31;
    const uint* L = (const uint*)latentB;
    int e0 = gwave * 8 + half * 4;
    if (e0 >= 2 * EP_EDGES) return;

    int ia[4], ib[4];
    #pragma unroll
    for (int u = 0; u < 4; ++u) {
        int edge = e0 + u;
        if (edge < EP_EDGES) {
            ia[u] = pos[edge];
            ib[u] = pos[EP_EDGES + edge];
        } else {
            int e2 = edge - EP_EDGES;
            ia[u] = neg[e2];
            ib[u] = neg[EP_EDGES + e2];
        }
    }
    uint la[4], lb[4];
    #pragma unroll
    for (int u = 0; u < 4; ++u) {
        la[u] = L[(size_t)ia[u] * 32 + sl];
        lb[u] = L[(size_t)ib[u] * 32 + sl];
    }
    float v[4];
    #pragma unroll
    for (int u = 0; u < 4; ++u)
        v[u] = bflo(la[u]) * bflo(lb[u]) + bfhi(la[u]) * bfhi(lb[u]);
    #pragma unroll
    for (int u = 0; u < 4; ++u) {
        float s = v[u];
        #pragma unroll
        for (int off = 16; off > 0; off >>= 1) s += __shfl_down(s, off, 64);
        if (sl == 0) out[e0 + u] = s;   // lane 0 (half 0) and lane 32 (half 1)
    }
}

// ---------------- launcher ----------------

extern "C" void kernel_launch(void* const* d_in, const int* in_sizes, int n_in,
                              void* d_out, int out_size, void* d_ws, size_t ws_size,
                              hipStream_t stream) {
    const float* x  = (const float*)d_in[0];     // [N,128]
    const float* W1 = (const float*)d_in[1];     // [128,128]
    const float* b1 = (const float*)d_in[2];     // [128]
    const float* W2 = (const float*)d_in[3];     // [128,64]
    const float* b2 = (const float*)d_in[4];     // [64]
    const int* edge_index = (const int*)d_in[5]; // [2,E] flat
    const int* pos = (const int*)d_in[6];        // [2,EP] flat
    const int* neg = (const int*)d_in[7];        // [2,EP] flat
    float* out = (float*)d_out;                  // [2*EP]

    const int* src = edge_index;
    const int* dst = edge_index + E_EDGES;

    // ws: dinv[N] | ends[N] | gcur[1024] | tbl[NCHUNK*NBUCK] | sorted[E] |
    //     csr[E] | W1T | W2T | [pad to 256B] | bufH[N*128] bf16 | bufR[N*128] bf16
    // bufH/bufR MUST be 256B-aligned: feature rows are 256B / 128B — R11's
    // misalignment (+1.2MB tbl shift) cost +43% FETCH in every random-row kernel.
    float*  dinv   = (float*)d_ws;
    int*    ends   = (int*)(dinv + N_NODES);
    int*    gcur   = ends + N_NODES;
    int*    tbl    = gcur + 1024;
    int*    sorted = tbl + NCHUNK * NBUCK;
    int*    csr    = sorted + E_EDGES;
    ushort* W1T    = (ushort*)(csr + E_EDGES);
    ushort* W2T    = W1T + 128 * 128;
    ushort* bufH   = (ushort*)(((uintptr_t)(W2T + 64 * 128) + 255) & ~(uintptr_t)255);
    ushort* bufR   = bufH + (size_t)N_NODES * 128;   // 25.6MB offset, stays 256B-aligned

    // 1) weights -> bf16 transposed (+ gcur zeroing)
    wprep_kernel<<<96, 256, 0, stream>>>(W1, W2, W1T, W2T, gcur);

    // 2) deterministic bucket sort: hist -> bucket scan -> chunk scan -> scatter
    bhist_kernel<<<NCHUNK, 256, 0, stream>>>(dst, gcur, tbl);
    bscan_kernel<<<1, 1024, 0, stream>>>(gcur);
    chunk_scan_kernel<<<NBUCK, 512, 0, stream>>>(tbl, gcur);
    bscatter_kernel<<<NCHUNK, 256, 0, stream>>>(src, dst, tbl, sorted);
    bucket_csr_kernel<<<NBUCK, 256, 0, stream>>>(sorted, gcur, csr, ends, dinv);

    const int GEMM_GRID = (N_NODES + 63) / 64;

    // 3) h0_s = (x @ W1) * dinv  (fp32 A converted in-register) -> bufH bf16
    gemm_mfma_kernel<128, true><<<GEMM_GRID, 256, 0, stream>>>(x, W1T, dinv, bufH, N_NODES);

    // 4) h_relu = relu(b1 + dinv * (self + Agg)) -> bufR bf16, feature-half split
    gather128h_kernel<<<2 * (N_NODES / 4), 256, 0, stream>>>(bufH, b1, dinv, ends, csr, bufR);

    // 5) l0_s = (h_relu @ W2) * dinv -> bufH bf16 [N,64]
    gemm_mfma_kernel<64, false><<<GEMM_GRID, 256, 0, stream>>>(bufR, W2T, dinv, bufH, N_NODES);

    // 6) latentB = b2 + dinv * (self + Agg) -> bufR packed bf16 [N,64], half split
    ushort* latentB = bufR;
    gather64h_kernel<<<2 * (N_NODES / 4), 256, 0, stream>>>(bufH, b2, dinv, ends, csr, latentB);

    // 7) decode on bf16 latent: 8 edges per wave -> 12500 blocks
    decode_kernel<<<(2 * EP_EDGES) / 32, 256, 0, stream>>>(latentB, pos, neg, out);
}

// Round 9
// 311.541 us; speedup vs baseline: 1.2741x; 1.2741x over previous
//
#include <hip/hip_runtime.h>

// Problem constants (from reference)
#define N_NODES 100000
#define F_IN    128
#define H_DIM   128
#define Z_DIM   64
#define E_EDGES 1600000
#define EP_EDGES 200000

// bucket sort params: bucket = dst >> 7  (128 nodes/bucket)
#define BSHIFT 7
#define NBUCK  ((N_NODES + 127) >> 7)          // 782
#define CHUNK  4096
#define NCHUNK ((E_EDGES + CHUNK - 1) / CHUNK) // 391

typedef __attribute__((ext_vector_type(8))) short short8;   // 8 bf16 = 4 VGPRs
typedef __attribute__((ext_vector_type(4))) float f32x4;    // MFMA C/D frag
typedef unsigned int uint;
typedef unsigned short ushort;

// bf16 helpers (round-to-nearest-even)
__device__ __forceinline__ ushort f2bf(float f) {
    uint u = __float_as_uint(f);
    u += 0x7fffu + ((u >> 16) & 1u);
    return (ushort)(u >> 16);
}
__device__ __forceinline__ float bflo(uint u) { return __uint_as_float(u << 16); }
__device__ __forceinline__ float bfhi(uint u) { return __uint_as_float(u & 0xffff0000u); }

// ---------------- weight prep (+ gcur zeroing folded in) ----------------

__global__ __launch_bounds__(256) void wprep_kernel(const float* __restrict__ W1,
                                                    const float* __restrict__ W2,
                                                    ushort* __restrict__ W1T,
                                                    ushort* __restrict__ W2T,
                                                    int* __restrict__ gcur) {
    int i = blockIdx.x * 256 + threadIdx.x;
    if (i < 1024) gcur[i] = 0;               // zero bucket totals
    if (i < 128 * 128) {
        int n = i >> 7, k = i & 127;
        W1T[i] = f2bf(W1[k * 128 + n]);
    }
    int j = i - 128 * 128;
    if (j >= 0 && j < 64 * 128) {
        int n = j >> 7, k = j & 127;
        W2T[j] = f2bf(W2[k * 64 + n]);
    }
}

// ---------------- bucket histogram: per-chunk LDS hist -> tbl + totals -----

__global__ __launch_bounds__(256) void bhist_kernel(const int* __restrict__ dst,
                                                    int* __restrict__ gcur,
                                                    int* __restrict__ tbl) {
    __shared__ int lh[NBUCK];
    for (int i = threadIdx.x; i < NBUCK; i += 256) lh[i] = 0;
    __syncthreads();
    int base = blockIdx.x * CHUNK;
    int end = min(base + CHUNK, E_EDGES);
    for (int e = base + threadIdx.x; e < end; e += 256)
        atomicAdd(&lh[dst[e] >> BSHIFT], 1);
    __syncthreads();
    int* trow = tbl + (size_t)blockIdx.x * NBUCK;
    for (int i = threadIdx.x; i < NBUCK; i += 256) {
        int c = lh[i];
        trow[i] = c;                         // per-chunk count (coalesced)
        if (c) atomicAdd(&gcur[i], c);       // bucket total
    }
}

// ---------------- exclusive scan over 782 bucket totals (single block) -----

__global__ __launch_bounds__(1024) void bscan_kernel(int* __restrict__ gc) {
    __shared__ int s[1024];
    int t = threadIdx.x;
    int v = (t < NBUCK) ? gc[t] : 0;
    s[t] = v;
    __syncthreads();
    #pragma unroll
    for (int off = 1; off < 1024; off <<= 1) {
        int x = (t >= off) ? s[t - off] : 0;
        __syncthreads();
        s[t] += x;
        __syncthreads();
    }
    if (t < NBUCK) gc[t] = s[t] - v;   // exclusive prefix = bucket starts
}

// ---------------- per-bucket scan over chunk counts ----------------

__global__ __launch_bounds__(512) void chunk_scan_kernel(int* __restrict__ tbl,
                                                         const int* __restrict__ gcur) {
    __shared__ int s[512];
    int b = blockIdx.x, t = threadIdx.x;
    int v = (t < NCHUNK) ? tbl[(size_t)t * NBUCK + b] : 0;
    s[t] = v;
    __syncthreads();
    #pragma unroll
    for (int off = 1; off < 512; off <<= 1) {
        int x = (t >= off) ? s[t - off] : 0;
        __syncthreads();
        s[t] += x;
        __syncthreads();
    }
    if (t < NCHUNK)
        tbl[(size_t)t * NBUCK + b] = gcur[b] + (s[t] - v);  // absolute base
}

// ---------------- bucket scatter: single pass, no global atomics -----------
// packed = (src << 7) | (dst & 127): src < 2^17, local dst 7 bits.

__global__ __launch_bounds__(256) void bscatter_kernel(const int* __restrict__ src,
                                                       const int* __restrict__ dst,
                                                       const int* __restrict__ tbl,
                                                       int* __restrict__ sorted) {
    __shared__ int lbase[NBUCK];
    int c = blockIdx.x;
    const int* trow = tbl + (size_t)c * NBUCK;
    for (int i = threadIdx.x; i < NBUCK; i += 256) lbase[i] = trow[i];  // coalesced
    __syncthreads();
    int base = c * CHUNK;
    int end = min(base + CHUNK, E_EDGES);
    for (int e = base + threadIdx.x; e < end; e += 256) {
        int d = dst[e];
        int p = atomicAdd(&lbase[d >> BSHIFT], 1);
        sorted[p] = (src[e] << 7) | (d & 127);
    }
}

// ---------------- fused per-bucket CSR build (per-wave hist/cursors) -------

__global__ __launch_bounds__(256) void bucket_csr_kernel(const int* __restrict__ sorted,
                                                         const int* __restrict__ gcur,
                                                         int* __restrict__ csr,
                                                         int* __restrict__ ends,
                                                         float* __restrict__ dinv) {
    __shared__ int lcnt[4][128], lcur[4][128];
    int b = blockIdx.x, t = threadIdx.x;
    int wave = t >> 6;
    int bstart = gcur[b];
    int bend = (b + 1 < NBUCK) ? gcur[b + 1] : E_EDGES;
    if (t < 128) { lcnt[0][t] = 0; lcnt[1][t] = 0; }
    else { int u = t - 128; lcnt[2][u] = 0; lcnt[3][u] = 0; }
    __syncthreads();
    for (int i = bstart + t; i < bend; i += 256)
        atomicAdd(&lcnt[wave][sorted[i] & 127], 1);
    __syncthreads();
    if (t < 64) {                         // wave 0: scan 128 node totals
        int w0a = lcnt[0][t], w1a = lcnt[1][t], w2a = lcnt[2][t], w3a = lcnt[3][t];
        int w0b = lcnt[0][t + 64], w1b = lcnt[1][t + 64], w2b = lcnt[2][t + 64], w3b = lcnt[3][t + 64];
        int c0 = w0a + w1a + w2a + w3a;
        int c1 = w0b + w1b + w2b + w3b;
        int s0 = c0;
        #pragma unroll
        for (int d = 1; d < 64; d <<= 1) {
            int x = __shfl_up(s0, d, 64);
            if (t >= d) s0 += x;
        }
        int tot0 = __shfl(s0, 63, 64);
        int s1 = c1;
        #pragma unroll
        for (int d = 1; d < 64; d <<= 1) {
            int x = __shfl_up(s1, d, 64);
            if (t >= d) s1 += x;
        }
        s1 += tot0;
        int basea = bstart + s0 - c0;     // start of node t
        int baseb = bstart + s1 - c1;     // start of node t+64
        lcur[0][t] = basea;
        lcur[1][t] = basea + w0a;
        lcur[2][t] = basea + w0a + w1a;
        lcur[3][t] = basea + w0a + w1a + w2a;
        lcur[0][t + 64] = baseb;
        lcur[1][t + 64] = baseb + w0b;
        lcur[2][t + 64] = baseb + w0b + w1b;
        lcur[3][t + 64] = baseb + w0b + w1b + w2b;
        int n0 = b * 128 + t, n1 = n0 + 64;
        if (n0 < N_NODES) { ends[n0] = bstart + s0; dinv[n0] = rsqrtf(1.0f + (float)c0); }
        if (n1 < N_NODES) { ends[n1] = bstart + s1; dinv[n1] = rsqrtf(1.0f + (float)c1); }
    }
    __syncthreads();
    for (int i = bstart + t; i < bend; i += 256) {
        int v = sorted[i];
        int p = atomicAdd(&lcur[wave][v & 127], 1);
        csr[p] = v >> 7;
    }
}

// ---------------- MFMA bf16 GEMM with dinv-prescaled bf16 output ----------

template<int NC, bool A_F32>
__global__ __launch_bounds__(256) void gemm_mfma_kernel(const void* __restrict__ Ap,
                                                        const ushort* __restrict__ BT,
                                                        const float* __restrict__ dinv,
                                                        ushort* __restrict__ C, int M) {
    constexpr int NT = NC / 16;
    __shared__ ushort Bs[4 * NT * 64 * 8];   // 32KB (NC=128) / 16KB (NC=64)

    for (int idx = threadIdx.x; idx < 4 * NT * 64; idx += 256) {
        int l   = idx & 63;
        int nt  = (idx >> 6) % NT;
        int kc  = idx / (64 * NT);
        int m16 = l & 15, quad = l >> 4;
        ((short8*)Bs)[idx] =
            *(const short8*)(BT + ((nt * 16 + m16) * 128 + kc * 32 + quad * 8));
    }
    __syncthreads();

    int wave = threadIdx.x >> 6, lane = threadIdx.x & 63;
    int m16 = lane & 15, quad = lane >> 4;
    int row0 = (blockIdx.x * 4 + wave) * 16;
    if (row0 >= M) return;
    int arow = row0 + m16;
    if (arow >= M) arow = M - 1;           // clamp loads; stores guarded

    f32x4 acc[NT];
    #pragma unroll
    for (int t = 0; t < NT; ++t) acc[t] = (f32x4){0.f, 0.f, 0.f, 0.f};

    #pragma unroll
    for (int kc = 0; kc < 4; ++kc) {
        short8 a;
        if (A_F32) {
            const float* A = (const float*)Ap;
            const float4* p = (const float4*)(A + (size_t)arow * 128 + kc * 32 + quad * 8);
            float4 x0 = p[0], x1 = p[1];
            a[0] = (short)f2bf(x0.x); a[1] = (short)f2bf(x0.y);
            a[2] = (short)f2bf(x0.z); a[3] = (short)f2bf(x0.w);
            a[4] = (short)f2bf(x1.x); a[5] = (short)f2bf(x1.y);
            a[6] = (short)f2bf(x1.z); a[7] = (short)f2bf(x1.w);
        } else {
            a = *(const short8*)((const ushort*)Ap + (size_t)arow * 128 + kc * 32 + quad * 8);
        }
        #pragma unroll
        for (int nt = 0; nt < NT; ++nt) {
            short8 b = ((const short8*)Bs)[(kc * NT + nt) * 64 + lane];
            acc[nt] = __builtin_amdgcn_mfma_f32_16x16x32_bf16(a, b, acc[nt], 0, 0, 0);
        }
    }

    #pragma unroll
    for (int r = 0; r < 4; ++r) {
        int row = row0 + quad * 4 + r;
        if (row < M) {
            float dr = dinv[row];
            #pragma unroll
            for (int nt = 0; nt < NT; ++nt)
                C[(size_t)row * NC + nt * 16 + m16] = f2bf(acc[nt][r] * dr);
        }
    }
}

// ---------------- gather FD=128: quarter-wave rows (16 lanes x uint4) ------
// BEST MEASURED (R2, 61.4us): one wave per node; indices for a 64-edge
// window fetched by ONE coalesced load and broadcast via __shfl; 16-edge
// chunks with 4 rows (4KB/wave) in flight per quarter. Tail uses full-exec
// clamped shuffles + predicated adds (ds_bpermute from inactive lanes is
// UNDEFINED — R1 bug). At ~61us this kernel sits at the L2/L3 transaction-
// service equilibrium (R8 falsified working-set splits; R4-6 falsified
// fusion; 3 schedules converge) — do not re-attack with scheduling.

__global__ __launch_bounds__(256, 8) void gather128_kernel(const ushort* __restrict__ feat,
                                                           const float* __restrict__ bias,
                                                           const float* __restrict__ dinv,
                                                           const int* __restrict__ ends,
                                                           const int* __restrict__ csr,
                                                           ushort* __restrict__ out) {
    int wave = threadIdx.x >> 6, lane = threadIdx.x & 63;
    int q = lane >> 4, ql = lane & 15;          // quarter id, lane-in-quarter
    int n = blockIdx.x * 4 + wave;
    const uint4* F = (const uint4*)feat;        // row = 16 x uint4 (256B)

    float a0 = 0.f, a1 = 0.f, a2 = 0.f, a3 = 0.f;
    float a4 = 0.f, a5 = 0.f, a6 = 0.f, a7 = 0.f;
    if (q == 0) {                               // self row counted once
        uint4 s = F[(uint)n * 16u + (uint)ql];
        a0 = bflo(s.x); a1 = bfhi(s.x); a2 = bflo(s.y); a3 = bfhi(s.y);
        a4 = bflo(s.z); a5 = bfhi(s.z); a6 = bflo(s.w); a7 = bfhi(s.w);
    }
    int j0 = n ? ends[n - 1] : 0, j1 = ends[n];
    for (int base = j0; base < j1; base += 64) {   // m, nch wave-uniform
        int m = min(64, j1 - base);
        int idxv = csr[base + min(lane, m - 1)];   // 64 indices, 1 coalesced load
        int nch = m >> 4;
        for (int c = 0; c < nch; ++c) {            // uniform: 16 edges/chunk
            int e = c * 16 + q;
            int s0 = __shfl(idxv, e, 64);
            int s1 = __shfl(idxv, e + 4, 64);
            int s2 = __shfl(idxv, e + 8, 64);
            int s3 = __shfl(idxv, e + 12, 64);
            uint4 r0 = F[(uint)s0 * 16u + (uint)ql];
            uint4 r1 = F[(uint)s1 * 16u + (uint)ql];
            uint4 r2 = F[(uint)s2 * 16u + (uint)ql];
            uint4 r3 = F[(uint)s3 * 16u + (uint)ql];
            a0 += bflo(r0.x) + bflo(r1.x) + bflo(r2.x) + bflo(r3.x);
            a1 += bfhi(r0.x) + bfhi(r1.x) + bfhi(r2.x) + bfhi(r3.x);
            a2 += bflo(r0.y) + bflo(r1.y) + bflo(r2.y) + bflo(r3.y);
            a3 += bfhi(r0.y) + bfhi(r1.y) + bfhi(r2.y) + bfhi(r3.y);
            a4 += bflo(r0.z) + bflo(r1.z) + bflo(r2.z) + bflo(r3.z);
            a5 += bfhi(r0.z) + bfhi(r1.z) + bfhi(r2.z) + bfhi(r3.z);
            a6 += bflo(r0.w) + bflo(r1.w) + bflo(r2.w) + bflo(r3.w);
            a7 += bfhi(r0.w) + bfhi(r1.w) + bfhi(r2.w) + bfhi(r3.w);
        }
        if (nch * 16 < m) {                        // uniform tail guard
            int e = nch * 16 + q;
            int mc = m - 1;
            // full-exec shuffles with clamped source lanes (all < 64)
            int t0 = __shfl(idxv, min(e,      mc), 64);
            int t1 = __shfl(idxv, min(e + 4,  mc), 64);
            int t2 = __shfl(idxv, min(e + 8,  mc), 64);
            int t3 = __shfl(idxv, min(e + 12, mc), 64);
            // unconditional loads (clamped = valid rows), predicated adds
            uint4 r0 = F[(uint)t0 * 16u + (uint)ql];
            uint4 r1 = F[(uint)t1 * 16u + (uint)ql];
            uint4 r2 = F[(uint)t2 * 16u + (uint)ql];
            uint4 r3 = F[(uint)t3 * 16u + (uint)ql];
            if (e < m) {
                a0 += bflo(r0.x); a1 += bfhi(r0.x); a2 += bflo(r0.y); a3 += bfhi(r0.y);
                a4 += bflo(r0.z); a5 += bfhi(r0.z); a6 += bflo(r0.w); a7 += bfhi(r0.w);
            }
            if (e + 4 < m) {
                a0 += bflo(r1.x); a1 += bfhi(r1.x); a2 += bflo(r1.y); a3 += bfhi(r1.y);
                a4 += bflo(r1.z); a5 += bfhi(r1.z); a6 += bflo(r1.w); a7 += bfhi(r1.w);
            }
            if (e + 8 < m) {
                a0 += bflo(r2.x); a1 += bfhi(r2.x); a2 += bflo(r2.y); a3 += bfhi(r2.y);
                a4 += bflo(r2.z); a5 += bfhi(r2.z); a6 += bflo(r2.w); a7 += bfhi(r2.w);
            }
            if (e + 12 < m) {
                a0 += bflo(r3.x); a1 += bfhi(r3.x); a2 += bflo(r3.y); a3 += bfhi(r3.y);
                a4 += bflo(r3.z); a5 += bfhi(r3.z); a6 += bflo(r3.w); a7 += bfhi(r3.w);
            }
        }
    }
    a0 += __shfl_xor(a0, 16, 64); a0 += __shfl_xor(a0, 32, 64);
    a1 += __shfl_xor(a1, 16, 64); a1 += __shfl_xor(a1, 32, 64);
    a2 += __shfl_xor(a2, 16, 64); a2 += __shfl_xor(a2, 32, 64);
    a3 += __shfl_xor(a3, 16, 64); a3 += __shfl_xor(a3, 32, 64);
    a4 += __shfl_xor(a4, 16, 64); a4 += __shfl_xor(a4, 32, 64);
    a5 += __shfl_xor(a5, 16, 64); a5 += __shfl_xor(a5, 32, 64);
    a6 += __shfl_xor(a6, 16, 64); a6 += __shfl_xor(a6, 32, 64);
    a7 += __shfl_xor(a7, 16, 64); a7 += __shfl_xor(a7, 32, 64);
    if (q == 0) {
        float dn = dinv[n];
        const float4* bp = (const float4*)(bias + ql * 8);
        float4 b0 = bp[0], b1v = bp[1];
        float r0 = fmaxf(b0.x + dn * a0, 0.f);
        float r1 = fmaxf(b0.y + dn * a1, 0.f);
        float r2 = fmaxf(b0.z + dn * a2, 0.f);
        float r3 = fmaxf(b0.w + dn * a3, 0.f);
        float r4 = fmaxf(b1v.x + dn * a4, 0.f);
        float r5 = fmaxf(b1v.y + dn * a5, 0.f);
        float r6 = fmaxf(b1v.z + dn * a6, 0.f);
        float r7 = fmaxf(b1v.w + dn * a7, 0.f);
        uint4 o;
        o.x = (uint)f2bf(r0) | ((uint)f2bf(r1) << 16);
        o.y = (uint)f2bf(r2) | ((uint)f2bf(r3) << 16);
        o.z = (uint)f2bf(r4) | ((uint)f2bf(r5) << 16);
        o.w = (uint)f2bf(r6) | ((uint)f2bf(r7) << 16);
        ((uint4*)out)[(uint)n * 16u + (uint)ql] = o;
    }
}

// ---------------- gather FD=64: half-wave edge pairing, uint loads ---------
// BEST MEASURED (R4 delta ~ -4us vs R2's): lanes 0-31 take edge e, lanes
// 32-63 edge e+1; each lane loads a full uint (2 channels). Edge indices
// wave-uniform via readlane; half-select is one cndmask; one shfl_xor(32)
// pair merges parities.

__global__ __launch_bounds__(256, 8) void gather64_kernel(const ushort* __restrict__ feat,
                                                          const float* __restrict__ bias,
                                                          const float* __restrict__ dinv,
                                                          const int* __restrict__ ends,
                                                          const int* __restrict__ csr,
                                                          ushort* __restrict__ outB) {
    int wave = threadIdx.x >> 6, lane = threadIdx.x & 63;
    int g = lane >> 5, c = lane & 31;           // half id, uint column
    int n = blockIdx.x * 4 + wave;
    const uint* F = (const uint*)feat;          // row = 32 x uint (128B)

    float a0 = 0.f, a1 = 0.f;
    uint su = F[(uint)n * 32u + (uint)c];       // both halves same addr
    if (g == 0) { a0 = bflo(su); a1 = bfhi(su); }   // self counted once

    int j0 = n ? ends[n - 1] : 0, j1 = ends[n];
    j0 = __builtin_amdgcn_readfirstlane(j0);
    j1 = __builtin_amdgcn_readfirstlane(j1);

    for (int base = j0; base < j1; base += 64) {
        int m = min(64, j1 - base);
        int idxv = __builtin_nontemporal_load(csr + base + min(lane, m - 1));
        int e = 0;
        for (; e + 8 <= m; e += 8) {            // 4 pair-loads = 8 edges
            int sa0 = __builtin_amdgcn_readlane(idxv, e + 0);
            int sb0 = __builtin_amdgcn_readlane(idxv, e + 1);
            int sa1 = __builtin_amdgcn_readlane(idxv, e + 2);
            int sb1 = __builtin_amdgcn_readlane(idxv, e + 3);
            int sa2 = __builtin_amdgcn_readlane(idxv, e + 4);
            int sb2 = __builtin_amdgcn_readlane(idxv, e + 5);
            int sa3 = __builtin_amdgcn_readlane(idxv, e + 6);
            int sb3 = __builtin_amdgcn_readlane(idxv, e + 7);
            uint p0 = (uint)(g ? sb0 : sa0);
            uint p1 = (uint)(g ? sb1 : sa1);
            uint p2 = (uint)(g ? sb2 : sa2);
            uint p3 = (uint)(g ? sb3 : sa3);
            uint r0 = F[p0 * 32u + (uint)c];
            uint r1 = F[p1 * 32u + (uint)c];
            uint r2 = F[p2 * 32u + (uint)c];
            uint r3 = F[p3 * 32u + (uint)c];
            a0 += bflo(r0) + bflo(r1);
            a1 += bfhi(r0) + bfhi(r1);
            a0 += bflo(r2) + bflo(r3);
            a1 += bfhi(r2) + bfhi(r3);
        }
        for (; e + 2 <= m; e += 2) {            // pair tail
            int sa = __builtin_amdgcn_readlane(idxv, e);
            int sb = __builtin_amdgcn_readlane(idxv, e + 1);
            uint p = (uint)(g ? sb : sa);
            uint r = F[p * 32u + (uint)c];
            a0 += bflo(r); a1 += bfhi(r);
        }
        if (e < m) {                            // single leftover edge
            int s = __builtin_amdgcn_readlane(idxv, e);
            uint r = F[(uint)s * 32u + (uint)c];
            if (g == 0) { a0 += bflo(r); a1 += bfhi(r); }
        }
    }
    a0 += __shfl_xor(a0, 32, 64);
    a1 += __shfl_xor(a1, 32, 64);
    if (g == 0) {
        float dn = dinv[n];
        float2 bv = ((const float2*)bias)[c];
        float o0 = bv.x + dn * a0;
        float o1 = bv.y + dn * a1;
        ((uint*)outB)[(uint)n * 32u + (uint)c] = (uint)f2bf(o0) | ((uint)f2bf(o1) << 16);
    }
}

// ---------------- decoder: bf16 latent, half-wave per edge, 8 edges/wave ---

__global__ __launch_bounds__(256) void decode_kernel(const ushort* __restrict__ latentB,
                                                     const int* __restrict__ pos,
                                                     const int* __restrict__ neg,
                                                     float* __restrict__ out) {
    int gwave = (blockIdx.x * 256 + threadIdx.x) >> 6;
    int lane = threadIdx.x & 63;
    int half = lane >> 5, sl = lane & 31;
    const uint* L = (const uint*)latentB;
    int e0 = gwave * 8 + half * 4;
    if (e0 >= 2 * EP_EDGES) return;

    int ia[4], ib[4];
    #pragma unroll
    for (int u = 0; u < 4; ++u) {
        int edge = e0 + u;
        if (edge < EP_EDGES) {
            ia[u] = pos[edge];
            ib[u] = pos[EP_EDGES + edge];
        } else {
            int e2 = edge - EP_EDGES;
            ia[u] = neg[e2];
            ib[u] = neg[EP_EDGES + e2];
        }
    }
    uint la[4], lb[4];
    #pragma unroll
    for (int u = 0; u < 4; ++u) {
        la[u] = L[(size_t)ia[u] * 32 + sl];
        lb[u] = L[(size_t)ib[u] * 32 + sl];
    }
    float v[4];
    #pragma unroll
    for (int u = 0; u < 4; ++u)
        v[u] = bflo(la[u]) * bflo(lb[u]) + bfhi(la[u]) * bfhi(lb[u]);
    #pragma unroll
    for (int u = 0; u < 4; ++u) {
        float s = v[u];
        #pragma unroll
        for (int off = 16; off > 0; off >>= 1) s += __shfl_down(s, off, 64);
        if (sl == 0) out[e0 + u] = s;   // lane 0 (half 0) and lane 32 (half 1)
    }
}

// ---------------- launcher ----------------

extern "C" void kernel_launch(void* const* d_in, const int* in_sizes, int n_in,
                              void* d_out, int out_size, void* d_ws, size_t ws_size,
                              hipStream_t stream) {
    const float* x  = (const float*)d_in[0];     // [N,128]
    const float* W1 = (const float*)d_in[1];     // [128,128]
    const float* b1 = (const float*)d_in[2];     // [128]
    const float* W2 = (const float*)d_in[3];     // [128,64]
    const float* b2 = (const float*)d_in[4];     // [64]
    const int* edge_index = (const int*)d_in[5]; // [2,E] flat
    const int* pos = (const int*)d_in[6];        // [2,EP] flat
    const int* neg = (const int*)d_in[7];        // [2,EP] flat
    float* out = (float*)d_out;                  // [2*EP]

    const int* src = edge_index;
    const int* dst = edge_index + E_EDGES;

    // ws: dinv[N] | ends[N] | gcur[1024] | tbl[NCHUNK*NBUCK] | sorted[E] |
    //     csr[E] | W1T | W2T | [pad to 256B] | bufH[N*128] bf16 | bufR[N*128] bf16
    // bufH/bufR MUST be 256B-aligned: feature rows are 256B / 128B — R11's
    // misalignment (+1.2MB tbl shift) cost +43% FETCH in every random-row kernel.
    float*  dinv   = (float*)d_ws;
    int*    ends   = (int*)(dinv + N_NODES);
    int*    gcur   = ends + N_NODES;
    int*    tbl    = gcur + 1024;
    int*    sorted = tbl + NCHUNK * NBUCK;
    int*    csr    = sorted + E_EDGES;
    ushort* W1T    = (ushort*)(csr + E_EDGES);
    ushort* W2T    = W1T + 128 * 128;
    ushort* bufH   = (ushort*)(((uintptr_t)(W2T + 64 * 128) + 255) & ~(uintptr_t)255);
    ushort* bufR   = bufH + (size_t)N_NODES * 128;   // 25.6MB offset, stays 256B-aligned

    // 1) weights -> bf16 transposed (+ gcur zeroing)
    wprep_kernel<<<96, 256, 0, stream>>>(W1, W2, W1T, W2T, gcur);

    // 2) deterministic bucket sort: hist -> bucket scan -> chunk scan -> scatter
    bhist_kernel<<<NCHUNK, 256, 0, stream>>>(dst, gcur, tbl);
    bscan_kernel<<<1, 1024, 0, stream>>>(gcur);
    chunk_scan_kernel<<<NBUCK, 512, 0, stream>>>(tbl, gcur);
    bscatter_kernel<<<NCHUNK, 256, 0, stream>>>(src, dst, tbl, sorted);
    bucket_csr_kernel<<<NBUCK, 256, 0, stream>>>(sorted, gcur, csr, ends, dinv);

    const int GEMM_GRID = (N_NODES + 63) / 64;

    // 3) h0_s = (x @ W1) * dinv  (fp32 A converted in-register) -> bufH bf16
    gemm_mfma_kernel<128, true><<<GEMM_GRID, 256, 0, stream>>>(x, W1T, dinv, bufH, N_NODES);

    // 4) h_relu = relu(b1 + dinv * (self + Agg)) -> bufR bf16
    gather128_kernel<<<N_NODES / 4, 256, 0, stream>>>(bufH, b1, dinv, ends, csr, bufR);

    // 5) l0_s = (h_relu @ W2) * dinv -> bufH bf16 [N,64]
    gemm_mfma_kernel<64, false><<<GEMM_GRID, 256, 0, stream>>>(bufR, W2T, dinv, bufH, N_NODES);

    // 6) latentB = b2 + dinv * (self + Agg) -> bufR packed bf16 [N,64]
    ushort* latentB = bufR;
    gather64_kernel<<<N_NODES / 4, 256, 0, stream>>>(bufH, b2, dinv, ends, csr, latentB);

    // 7) decode on bf16 latent: 8 edges per wave -> 12500 blocks
    decode_kernel<<<(2 * EP_EDGES) / 32, 256, 0, stream>>>(latentB, pos, neg, out);
}